// Round 9
// baseline (39.368 us; speedup 1.0000x reference)
//
#include <hip/hip_runtime.h>

#define BATCHES 4
#define NPTS    8192
#define INF32   3.0e38f

typedef _Float16 f16x8  __attribute__((ext_vector_type(8)));
typedef float    f32x16 __attribute__((ext_vector_type(16)));

// ---------------- prep: pack A-format and B-format 16-slot f16 vectors ----
// A-vec (pt p):  [ph0..2, pl0..2, ph0..2, qh, ql, 1, 1, 0,0,0]
// B-vec (pt p):  [-2ph0..2, -2ph0..2, -2pl0..2, 1, 1, qh, ql, 0,0,0]
// dot(Avec(u), Bvec(v)) = |u|^2 + |v|^2 - 2*(uh.vh + ul.vh + uh.vl)  (err ~1e-5)
// Packs BOTH formats for BOTH x and y (double-GEMM: D(x,y) and D(y,x)).
// Also initializes the 65536-word min buffer to +3.39e38 bits.
__device__ inline void fsplit(float v, _Float16& h, _Float16& l) {
    h = (_Float16)v;
    l = (_Float16)(v - (float)h);
}

__device__ inline void pack_point(float p0, float p1, float p2,
                                  _Float16* __restrict__ avec,
                                  _Float16* __restrict__ bvec)
{
    _Float16 h[3], l[3];
    fsplit(p0, h[0], l[0]); fsplit(p1, h[1], l[1]); fsplit(p2, h[2], l[2]);
    float q = fmaf(p2, p2, fmaf(p1, p1, p0 * p0));
    _Float16 qh, ql;
    fsplit(q, qh, ql);

    __align__(16) _Float16 av[16];
    __align__(16) _Float16 bv[16];
    #pragma unroll
    for (int k = 0; k < 3; ++k) {
        av[k]     = h[k];
        av[3 + k] = l[k];
        av[6 + k] = h[k];
        bv[k]     = (_Float16)(-2.0f * (float)h[k]);
        bv[3 + k] = bv[k];
        bv[6 + k] = (_Float16)(-2.0f * (float)l[k]);
    }
    av[9] = qh; av[10] = ql; av[11] = (_Float16)1.0f; av[12] = (_Float16)1.0f;
    bv[9] = (_Float16)1.0f; bv[10] = (_Float16)1.0f; bv[11] = qh; bv[12] = ql;
    av[13] = av[14] = av[15] = (_Float16)0.0f;
    bv[13] = bv[14] = bv[15] = (_Float16)0.0f;

    ((int4*)avec)[0] = ((int4*)av)[0]; ((int4*)avec)[1] = ((int4*)av)[1];
    ((int4*)bvec)[0] = ((int4*)bv)[0]; ((int4*)bvec)[1] = ((int4*)bv)[1];
}

__global__ __launch_bounds__(256) void chamfer_prep(
    const float* __restrict__ x, const float* __restrict__ y,
    _Float16* __restrict__ pAx, _Float16* __restrict__ pBx,
    _Float16* __restrict__ pAy, _Float16* __restrict__ pBy,
    int* __restrict__ mininit /* 65536 ints */)
{
    int i = blockIdx.x * 256 + threadIdx.x;     // point id 0..32767
    mininit[i]         = 0x7F7F7F7F;
    mininit[i + 32768] = 0x7F7F7F7F;

    const float* xp = x + (size_t)i * 3;
    const float* yp = y + (size_t)i * 3;
    pack_point(xp[0], xp[1], xp[2], pAx + (size_t)i * 16, pBx + (size_t)i * 16);
    pack_point(yp[0], yp[1], yp[2], pAy + (size_t)i * 16, pBy + (size_t)i * 16);
}

// ---------------- main: double-GEMM, register-only row-min -----------------
// grid 1024 = dir(2) x batch(4) x strip(32: 256 rows) x chunk(4: 2048 cols)
// dir0: A=x rows, B=y cols -> min over y per x-row.  dir1: swapped.
// wave owns 64 rows (2 row-tiles af0/af1), loops 64 col-tiles.
// Inner body (2 col-tiles): 2 B-loads + 4 MFMA + 32 v_min3. No LDS/shfl/atomic.
// A-frag: lane(row=l&31, k=(l>>5)*8+i); B-frag: lane(col=l&31, same k).
// D: col=l&31, row=(reg&3)+8*(reg>>2)+4*(l>>5)  [m74/m101].
__global__ __launch_bounds__(256, 4) void chamfer_mfma(
    const _Float16* __restrict__ pAx, const _Float16* __restrict__ pBx,
    const _Float16* __restrict__ pAy, const _Float16* __restrict__ pBy,
    float* __restrict__ minall /* [2][4][8192]: dir0 x-mins, dir1 y-mins */)
{
    int bid   = blockIdx.x;
    int dir   = bid >> 9;
    int rem   = bid & 511;
    int b     = rem >> 7;
    int rem2  = rem & 127;
    int strip = rem2 >> 2;         // 0..31 -> 256 rows
    int chunk = rem2 & 3;          // 0..3  -> 2048 cols
    int tid   = threadIdx.x;
    int wv    = tid >> 6, lane = tid & 63;
    int lo    = lane & 31, hi = lane >> 5;

    const _Float16* Adata = ((dir == 0) ? pAx : pAy) + (size_t)b * NPTS * 16;
    const _Float16* Bdata = ((dir == 0) ? pBy : pBx) + (size_t)b * NPTS * 16;
    float* outMin = minall + ((size_t)dir << 15) + (size_t)b * NPTS;

    int rw = strip * 256 + wv * 64;    // wave's row base (2 row-tiles)
    int c0 = chunk * 2048;             // block's col base

    f16x8 af0 = *(const f16x8*)(Adata + (size_t)(rw + lo) * 16 + hi * 8);
    f16x8 af1 = *(const f16x8*)(Adata + (size_t)(rw + 32 + lo) * 16 + hi * 8);

    float rmin0[16], rmin1[16];
    #pragma unroll
    for (int r = 0; r < 16; ++r) { rmin0[r] = INF32; rmin1[r] = INF32; }

    const f32x16 zero = {0.f,0.f,0.f,0.f,0.f,0.f,0.f,0.f,
                         0.f,0.f,0.f,0.f,0.f,0.f,0.f,0.f};

    auto loadB = [&](int t) -> f16x8 {
        return *(const f16x8*)(Bdata + (size_t)(c0 + (t << 5) + lo) * 16 + hi * 8);
    };

    f16x8 b0 = loadB(0), b1 = loadB(1);
    #pragma unroll 1
    for (int t = 0; t < 64; t += 2) {
        f16x8 n0 = loadB((t + 2) & 63);
        f16x8 n1 = loadB((t + 3) & 63);
        f32x16 A0 = __builtin_amdgcn_mfma_f32_32x32x16_f16(af0, b0, zero, 0, 0, 0);
        f32x16 A1 = __builtin_amdgcn_mfma_f32_32x32x16_f16(af0, b1, zero, 0, 0, 0);
        #pragma unroll
        for (int r = 0; r < 16; ++r)
            rmin0[r] = fminf(fminf(A0[r], A1[r]), rmin0[r]);   // v_min3
        f32x16 B0 = __builtin_amdgcn_mfma_f32_32x32x16_f16(af1, b0, zero, 0, 0, 0);
        f32x16 B1 = __builtin_amdgcn_mfma_f32_32x32x16_f16(af1, b1, zero, 0, 0, 0);
        #pragma unroll
        for (int r = 0; r < 16; ++r)
            rmin1[r] = fminf(fminf(B0[r], B1[r]), rmin1[r]);   // v_min3
        b0 = n0; b1 = n1;
    }

    // fold row-mins across cols (lane bits 0-4), then atomicMin per row.
    #pragma unroll
    for (int r = 0; r < 16; ++r) {
        float v = rmin0[r];
        v = fminf(v, __shfl_xor(v, 1, 64));
        v = fminf(v, __shfl_xor(v, 2, 64));
        v = fminf(v, __shfl_xor(v, 4, 64));
        v = fminf(v, __shfl_xor(v, 8, 64));
        v = fminf(v, __shfl_xor(v, 16, 64));
        float w = rmin1[r];
        w = fminf(w, __shfl_xor(w, 1, 64));
        w = fminf(w, __shfl_xor(w, 2, 64));
        w = fminf(w, __shfl_xor(w, 4, 64));
        w = fminf(w, __shfl_xor(w, 8, 64));
        w = fminf(w, __shfl_xor(w, 16, 64));
        if (lo == 0) {
            int rr = (r & 3) + ((r >> 2) << 3) + (hi << 2);
            atomicMin((int*)&outMin[rw + rr],
                      __float_as_int(fmaxf(v, 0.f)));
            atomicMin((int*)&outMin[rw + 32 + rr],
                      __float_as_int(fmaxf(w, 0.f)));
        }
    }
}

// ---------------- final reduction (fixed-tree, deterministic) --------------
__global__ __launch_bounds__(256) void chamfer_reduce1(
    const float* __restrict__ minbuf, double* __restrict__ partials)
{
    int base = blockIdx.x * 1024 + threadIdx.x * 4;
    float4 v = *reinterpret_cast<const float4*>(minbuf + base);
    double s = ((double)v.x + (double)v.y) + ((double)v.z + (double)v.w);
    #pragma unroll
    for (int off = 32; off > 0; off >>= 1) s += __shfl_down(s, off, 64);
    __shared__ double sd[4];
    int wid = threadIdx.x >> 6;
    if ((threadIdx.x & 63) == 0) sd[wid] = s;
    __syncthreads();
    if (threadIdx.x == 0)
        partials[blockIdx.x] = (sd[0] + sd[1]) + (sd[2] + sd[3]);
}

__global__ __launch_bounds__(64) void chamfer_reduce2(
    const double* __restrict__ partials, float* __restrict__ out)
{
    double s = partials[threadIdx.x];
    #pragma unroll
    for (int off = 32; off > 0; off >>= 1) s += __shfl_down(s, off, 64);
    if (threadIdx.x == 0)
        out[0] = (float)(s / (double)(BATCHES * NPTS));
}

extern "C" void kernel_launch(void* const* d_in, const int* in_sizes, int n_in,
                              void* d_out, int out_size, void* d_ws, size_t ws_size,
                              hipStream_t stream)
{
    const float* x = (const float*)d_in[0];
    const float* y = (const float*)d_in[1];
    float* out = (float*)d_out;

    // ws layout (~4.5 MB):
    float*    minall = (float*)d_ws;                       // 65536 f = 256 KB
    _Float16* pAx = (_Float16*)(minall + 65536);           // 1 MB each
    _Float16* pBx = pAx + (size_t)BATCHES * NPTS * 16;
    _Float16* pAy = pBx + (size_t)BATCHES * NPTS * 16;
    _Float16* pBy = pAy + (size_t)BATCHES * NPTS * 16;
    double*   partials = (double*)(pBy + (size_t)BATCHES * NPTS * 16);

    chamfer_prep<<<BATCHES * NPTS / 256, 256, 0, stream>>>(
        x, y, pAx, pBx, pAy, pBy, (int*)minall);
    chamfer_mfma<<<1024, 256, 0, stream>>>(pAx, pBx, pAy, pBy, minall);
    chamfer_reduce1<<<64, 256, 0, stream>>>(minall, partials);
    chamfer_reduce2<<<1, 64, 0, stream>>>(partials, out);
}